// Round 12
// baseline (9322.720 us; speedup 1.0000x reference)
//
#include <hip/hip_runtime.h>
#include <math.h>

// LatentFNO: B=32, T=24, R=512, W=128, M=64 modes, 4 layers, 12 steps.
// Round 11: r10's cooperative launch never executed (output all-zero ->
// hipLaunchCooperativeKernel error, unchecked). Same persistent kernel,
// now launched as a PLAIN <<<256,256>>> grid (1 block/CU, co-resident by
// construction) with a hand-rolled device-scope grid barrier (agent-scope
// atomics + __threadfence, sense-reversing; state in d_ws, memset per call).
// Phase bodies unchanged from r8/r9 (bitwise-identical math).

#define NB 32
#define NR 512
#define NW 128
#define NM 64
#define NTH 24
#define NLAY 4
#define NSTEPS 12
#define SEQROWS 36

typedef unsigned short u16;
typedef unsigned int u32;
typedef __attribute__((ext_vector_type(8))) short bf16x8;
typedef __attribute__((ext_vector_type(4))) float f32x4;
#define MFMA16(a, b, c) __builtin_amdgcn_mfma_f32_16x16x32_bf16((a), (b), (c), 0, 0, 0)

__device__ __forceinline__ float gelu_exact(float x) {
    return 0.5f * x * (1.0f + erff(x * 0.70710678118654752f));
}
__device__ __forceinline__ float bf2f(u16 u) {
    union { u32 i; float f; } v; v.i = ((u32)u) << 16; return v.f;
}
__device__ __forceinline__ u16 f2bf_hi(float x) {
    union { float f; u32 i; } v; v.f = x; return (u16)(v.i >> 16);
}
__device__ __forceinline__ u16 f2bf_lo(float x) {
    float h = bf2f(f2bf_hi(x));
    return f2bf_hi(x - h);
}
__device__ __forceinline__ bf16x8 negbf(bf16x8 a) {
#pragma unroll
    for (int i = 0; i < 8; i++) a[i] ^= (short)0x8000;
    return a;
}

// Hand-rolled grid barrier: bar[0]=arrive counter, bar[1]=generation.
// All 256 blocks are co-resident (grid == CU count, 1 block/CU).
__device__ __forceinline__ void grid_barrier(unsigned* bar) {
    __syncthreads();
    if (threadIdx.x == 0) {
        __threadfence();   // release prior writes to device scope (cross-XCD)
        unsigned my = __hip_atomic_load(&bar[1], __ATOMIC_RELAXED, __HIP_MEMORY_SCOPE_AGENT);
        unsigned prev = __hip_atomic_fetch_add(&bar[0], 1u, __ATOMIC_ACQ_REL, __HIP_MEMORY_SCOPE_AGENT);
        if (prev == 255u) {
            __hip_atomic_store(&bar[0], 0u, __ATOMIC_RELAXED, __HIP_MEMORY_SCOPE_AGENT);
            __hip_atomic_store(&bar[1], my + 1u, __ATOMIC_RELEASE, __HIP_MEMORY_SCOPE_AGENT);
        } else {
            while (__hip_atomic_load(&bar[1], __ATOMIC_ACQUIRE, __HIP_MEMORY_SCOPE_AGENT) == my) {
                __builtin_amdgcn_s_sleep(2);
            }
        }
        __threadfence();   // acquire: invalidate this CU/XCD caches
    }
    __syncthreads();
}

// ---------------------------------------------------------------------------
// Setup kernels (unchanged)
// ---------------------------------------------------------------------------
__global__ void build_tables_planes(u16* __restrict__ f1, u16* __restrict__ f2,
                                    u16* __restrict__ gt1, u16* __restrict__ gt2) {
    int idx = blockIdx.x * 256 + threadIdx.x;   // 65536: mc*512 + r
    int mc = idx >> 9, r = idx & 511, m = mc & 63;
    int p = (m * r) & 511;
    float a = (float)p * (1.0f / 256.0f);
    float c = cospif(a), s = sinpif(a);
    float Fv = (mc < 64) ? c : -s;
    float cm = (m == 0) ? (1.0f / 512.0f) : (2.0f / 512.0f);
    float Gv = (mc < 64) ? cm * c : ((m == 0) ? 0.0f : -cm * s);
    f1[idx] = f2bf_hi(Fv); f2[idx] = f2bf_lo(Fv);
    size_t g = (size_t)r * 128 + mc;
    gt1[g] = f2bf_hi(Gv); gt2[g] = f2bf_lo(Gv);
}

__global__ __launch_bounds__(256) void prep_specw(const float* __restrict__ wr, const float* __restrict__ wi,
                           u16* __restrict__ wr1, u16* __restrict__ wr2,
                           u16* __restrict__ wi1, u16* __restrict__ wi2) {
    __shared__ float tile[128][65];
    int l = blockIdx.x >> 7, o = blockIdx.x & 127;
    int tid = threadIdx.x;
    size_t sbase = (size_t)l * 1048576 + (size_t)o * 64;
    size_t dbase = (size_t)l * 64 * 16384 + (size_t)o * 128;
    for (int pass = 0; pass < 2; pass++) {
        const float* src = pass ? wi : wr;
        u16* d1 = pass ? wi1 : wr1;
        u16* d2 = pass ? wi2 : wr2;
        if (pass) __syncthreads();
        for (int e = tid; e < 8192; e += 256) {
            int i = e >> 6, m = e & 63;
            tile[i][m] = src[sbase + (size_t)i * 8192 + m];
        }
        __syncthreads();
        for (int e = tid; e < 4096; e += 256) {
            int m = e >> 6, i2 = (e & 63) * 2;
            float v0 = tile[i2][m], v1 = tile[i2 + 1][m];
            u32 hh = (u32)f2bf_hi(v0) | ((u32)f2bf_hi(v1) << 16);
            u32 ll = (u32)f2bf_lo(v0) | ((u32)f2bf_lo(v1) << 16);
            size_t d = dbase + (size_t)m * 16384 + i2;
            *(u32*)&d1[d] = hh;
            *(u32*)&d2[d] = ll;
        }
    }
}

__global__ void prep_cw(const float* __restrict__ cw, u16* __restrict__ c1, u16* __restrict__ c2) {
    int idx = blockIdx.x * 256 + threadIdx.x;   // 65536
    float v = cw[idx];
    c1[idx] = f2bf_hi(v); c2[idx] = f2bf_lo(v);
}

__global__ void prep_fc1t(const float* __restrict__ fc1_w,
                          u16* __restrict__ f11, u16* __restrict__ f12) {
    int idx = blockIdx.x * 256 + threadIdx.x;   // 32768: j*128 + c
    int j = idx >> 7, c = idx & 127;
    float v = fc1_w[(size_t)c * 256 + j];
    f11[idx] = f2bf_hi(v); f12[idx] = f2bf_lo(v);
}

__global__ void init_seq_kernel(const float* __restrict__ z, float* __restrict__ seq) {
    int idx = blockIdx.x * 256 + threadIdx.x;    // < 32*24*512
    int b = idx / (NTH * NR);
    int rem = idx - b * (NTH * NR);
    seq[(size_t)b * SEQROWS * NR + rem] = z[idx];
}

// ---------------------------------------------------------------------------
// Persistent kernel: whole 12-step rollout, 156 grid barriers.
// 256 blocks x 256 threads (1/CU). POOL = 70144 B shared, re-carved per phase.
// ---------------------------------------------------------------------------
struct PersistArgs {
    const u16 *f1, *f2, *gt1, *gt2;
    const u16 *wr1, *wr2, *wi1, *wi2;
    const u16 *cw1, *cw2;
    const float *conv_b;
    const u16 *f11, *f12;
    const float *fc1_b, *fc2_w, *fc2_b, *t_grid, *fc0_w, *fc0_b;
    float *seq, *preds;
    u16 *ht1, *ht2, *htc1, *htc2, *x1, *x2, *y1, *y2;
    unsigned *gbar;
};

__global__ __launch_bounds__(256, 1) void fno_persist(PersistArgs P) {
    __shared__ __align__(16) u16 POOL[35072];   // 70144 B
    const int bid = blockIdx.x;
    const int tid = threadIdx.x;
    const size_t htplane = (size_t)NB * NR * NW;

    // ======================= phase: fc0 (step 0) ===========================
    {
        float* wlds = (float*)POOL;             // 28*128
        float* blds = (float*)POOL + 3584;      // 128
        int b = bid >> 3, rblk = bid & 7;
        for (int t = tid; t < 28 * 128; t += 256) wlds[t] = P.fc0_w[t];
        if (tid < 128) blds[tid] = P.fc0_b[tid];
        __syncthreads();
        int lane = tid & 63, wq = tid >> 6;
        int r = rblk * 64 + lane;
        float sv[24];
        const float* sp = P.seq + ((size_t)b * SEQROWS + 0) * NR + r;
#pragma unroll
        for (int t = 0; t < 24; t++) sv[t] = sp[(size_t)t * NR];
        float tt = P.t_grid[b * 24 + 23] + 1.0f;
        float ang24 = 6.28318530717958647692f * tt * (1.0f / 24.0f);
        float ang168 = 6.28318530717958647692f * tt * (1.0f / 168.0f);
        float s24 = sinf(ang24), c24 = cosf(ang24), s168 = sinf(ang168);
        float xc = (float)r * (1.0f / 511.0f);
        size_t rowoff = ((size_t)b * NR + r) * NW;
#pragma unroll 2
        for (int w0 = 0; w0 < 32; w0 += 2) {
            float acc2[2];
#pragma unroll
            for (int q = 0; q < 2; q++) {
                int w = wq * 32 + w0 + q;
                float acc = blds[w];
#pragma unroll
                for (int t = 0; t < 24; t++) acc += sv[t] * wlds[t * 128 + w];
                acc += s24 * wlds[24 * 128 + w] + c24 * wlds[25 * 128 + w]
                     + s168 * wlds[26 * 128 + w] + xc * wlds[27 * 128 + w];
                acc2[q] = acc;
            }
            u16 h0 = f2bf_hi(acc2[0]), h1 = f2bf_hi(acc2[1]);
            u16 l0 = f2bf_lo(acc2[0]), l1 = f2bf_lo(acc2[1]);
            size_t off = rowoff + wq * 32 + w0;
            *(u32*)&P.ht1[off] = (u32)h0 | ((u32)h1 << 16);
            *(u32*)&P.ht2[off] = (u32)l0 | ((u32)l1 << 16);
            int w = wq * 32 + w0;
            size_t coff = ((size_t)b * 128 + w) * 512 + r;
            P.htc1[coff] = h0; P.htc1[coff + 512] = h1;
            P.htc2[coff] = l0; P.htc2[coff + 512] = l1;
        }
    }
    grid_barrier(P.gbar);

    for (int step = 0; step < NSTEPS; step++) {
        int cur = 0;
        for (int ly = 0; ly < NLAY; ly++) {
            // ======================= phase: dft ============================
            {
                u16* A1 = POOL;                  // [2][1280]
                u16* A2 = POOL + 2560;
                u16* B1 = POOL + 5120;           // [2][2560]
                u16* B2 = POOL + 10240;
                int bx = bid & 63;
                int mct = (bid >> 6) * 32;
                int b = bx >> 1, ch = bx & 1;
                int wid = tid >> 6, l = tid & 63;
                int wm0 = (wid >> 1) * 16, wn0 = (wid & 1) * 32;
                int arow = (l & 15), kgrp = (l >> 4) * 8;
                f32x4 acc0 = {0.f, 0.f, 0.f, 0.f}, acc1 = {0.f, 0.f, 0.f, 0.f};
                int pa_pl = tid >> 7, pa_row = (tid >> 2) & 31, pa_seg = tid & 3;
                const u16* asrc = (pa_pl ? P.f2 : P.f1) + (size_t)(mct + pa_row) * 512 + pa_seg * 8;
                int aoff = pa_row * 40 + pa_seg * 8;
                int b_row = (tid >> 2) & 63, b_seg = tid & 3;
                const u16* bsrc1 = P.htc1 + ((size_t)b * 128 + ch * 64 + b_row) * 512 + b_seg * 8;
                const u16* bsrc2 = P.htc2 + ((size_t)b * 128 + ch * 64 + b_row) * 512 + b_seg * 8;
                int boff = b_row * 40 + b_seg * 8;
                u16* adst = (pa_pl ? A2 : A1) + aoff;
                uint4 raO, rbO0, rbO1, raE, rbE0, rbE1;
                raO = *(const uint4*)(asrc); rbO0 = *(const uint4*)(bsrc1); rbO1 = *(const uint4*)(bsrc2);
                *(uint4*)(adst) = raO;
                *(uint4*)(B1 + boff) = rbO0;
                *(uint4*)(B2 + boff) = rbO1;
                raO = *(const uint4*)(asrc + 32); rbO0 = *(const uint4*)(bsrc1 + 32); rbO1 = *(const uint4*)(bsrc2 + 32);
                raE = *(const uint4*)(asrc + 64); rbE0 = *(const uint4*)(bsrc1 + 64); rbE1 = *(const uint4*)(bsrc2 + 64);
                __syncthreads();
#define DFT_COMPUTE(BUF)                                                             \
    {   bf16x8 a1 = *(const bf16x8*)&A1[(BUF) * 1280 + (wm0 + arow) * 40 + kgrp];    \
        bf16x8 a2 = *(const bf16x8*)&A2[(BUF) * 1280 + (wm0 + arow) * 40 + kgrp];    \
        bf16x8 b10 = *(const bf16x8*)&B1[(BUF) * 2560 + (wn0 + arow) * 40 + kgrp];   \
        bf16x8 b20 = *(const bf16x8*)&B2[(BUF) * 2560 + (wn0 + arow) * 40 + kgrp];   \
        bf16x8 b11 = *(const bf16x8*)&B1[(BUF) * 2560 + (wn0 + 16 + arow) * 40 + kgrp]; \
        bf16x8 b21 = *(const bf16x8*)&B2[(BUF) * 2560 + (wn0 + 16 + arow) * 40 + kgrp]; \
        acc0 = MFMA16(a1, b10, acc0);                                                \
        acc0 = MFMA16(a1, b20, acc0);                                                \
        acc0 = MFMA16(a2, b10, acc0);                                                \
        acc1 = MFMA16(a1, b11, acc1);                                                \
        acc1 = MFMA16(a1, b21, acc1);                                                \
        acc1 = MFMA16(a2, b11, acc1); }
                for (int k = 0; k < 16; k += 2) {
                    DFT_COMPUTE(0)
                    *(uint4*)(adst + 1280) = raO;
                    *(uint4*)(B1 + 2560 + boff) = rbO0;
                    *(uint4*)(B2 + 2560 + boff) = rbO1;
                    if (k < 13) {
                        int ko = (k + 3) * 32;
                        raO = *(const uint4*)(asrc + ko); rbO0 = *(const uint4*)(bsrc1 + ko); rbO1 = *(const uint4*)(bsrc2 + ko);
                    }
                    __syncthreads();
                    DFT_COMPUTE(1)
                    if (k < 14) {
                        *(uint4*)(adst) = raE;
                        *(uint4*)(B1 + boff) = rbE0;
                        *(uint4*)(B2 + boff) = rbE1;
                        if (k < 12) {
                            int ko = (k + 4) * 32;
                            raE = *(const uint4*)(asrc + ko); rbE0 = *(const uint4*)(bsrc1 + ko); rbE1 = *(const uint4*)(bsrc2 + ko);
                        }
                    }
                    __syncthreads();
                }
#undef DFT_COMPUTE
                int mcr = mct + wm0 + (l >> 4) * 4;
                int n0 = bx * 64 + wn0 + (l & 15);
#pragma unroll
                for (int j = 0; j < 4; j++) {
                    size_t o0 = (size_t)(mcr + j) * 4096 + n0;
                    P.x1[o0] = f2bf_hi(acc0[j]); P.x2[o0] = f2bf_lo(acc0[j]);
                    size_t o1 = o0 + 16;
                    P.x1[o1] = f2bf_hi(acc1[j]); P.x2[o1] = f2bf_lo(acc1[j]);
                }
            }
            grid_barrier(P.gbar);

            // ======================= phase: modemix ========================
            {
                int m = bid & 63, oq = bid >> 6;
                int wid = tid >> 6, l = tid & 63;
                int wo0 = (wid >> 1) * 16, wb0 = (wid & 1) * 16;
                int arow = l & 15, kgrp = (l >> 4) * 8;
                size_t wbase = (((size_t)ly * 64 + m) * 128 + oq * 32) * 128;
#pragma unroll
                for (int q = 0; q < 16; q++) {
                    const int slab = q >> 1;
                    int rr = ((q & 1) << 4) + (tid >> 4);
                    int seg = tid & 15;
                    const u16* src;
                    if      (slab == 0) src = P.wr1 + wbase + (size_t)rr * 128 + seg * 8;
                    else if (slab == 1) src = P.wr2 + wbase + (size_t)rr * 128 + seg * 8;
                    else if (slab == 2) src = P.wi1 + wbase + (size_t)rr * 128 + seg * 8;
                    else if (slab == 3) src = P.wi2 + wbase + (size_t)rr * 128 + seg * 8;
                    else if (slab == 4) src = P.x1 + (size_t)m * 4096 + rr * 128 + seg * 8;
                    else if (slab == 5) src = P.x2 + (size_t)m * 4096 + rr * 128 + seg * 8;
                    else if (slab == 6) src = P.x1 + (size_t)(64 + m) * 4096 + rr * 128 + seg * 8;
                    else                src = P.x2 + (size_t)(64 + m) * 4096 + rr * 128 + seg * 8;
                    *(uint4*)&POOL[slab * 4352 + rr * 136 + seg * 8] = *(const uint4*)src;
                }
                __syncthreads();
                f32x4 ar = {0.f, 0.f, 0.f, 0.f}, ai = {0.f, 0.f, 0.f, 0.f};
                int aoB = (wo0 + arow) * 136 + kgrp;
                int boB = (wb0 + arow) * 136 + kgrp;
#pragma unroll
                for (int kg = 0; kg < 4; kg++) {
                    int ao = aoB + kg * 32;
                    int bo = boB + kg * 32;
                    bf16x8 Wr1 = *(const bf16x8*)&POOL[0 * 4352 + ao];
                    bf16x8 Wr2 = *(const bf16x8*)&POOL[1 * 4352 + ao];
                    bf16x8 Wi1 = *(const bf16x8*)&POOL[2 * 4352 + ao];
                    bf16x8 Wi2 = *(const bf16x8*)&POOL[3 * 4352 + ao];
                    bf16x8 Xr1 = *(const bf16x8*)&POOL[4 * 4352 + bo];
                    bf16x8 Xr2 = *(const bf16x8*)&POOL[5 * 4352 + bo];
                    bf16x8 Xi1 = *(const bf16x8*)&POOL[6 * 4352 + bo];
                    bf16x8 Xi2 = *(const bf16x8*)&POOL[7 * 4352 + bo];
                    bf16x8 nWi1 = negbf(Wi1), nWi2 = negbf(Wi2);
                    ar = MFMA16(Wr1, Xr1, ar); ar = MFMA16(Wr1, Xr2, ar); ar = MFMA16(Wr2, Xr1, ar);
                    ar = MFMA16(nWi1, Xi1, ar); ar = MFMA16(nWi1, Xi2, ar); ar = MFMA16(nWi2, Xi1, ar);
                    ai = MFMA16(Wi1, Xr1, ai); ai = MFMA16(Wi1, Xr2, ai); ai = MFMA16(Wi2, Xr1, ai);
                    ai = MFMA16(Wr1, Xi1, ai); ai = MFMA16(Wr1, Xi2, ai); ai = MFMA16(Wr2, Xi1, ai);
                }
                int ob = oq * 32 + wo0 + (l >> 4) * 4;
                int bb = wb0 + (l & 15);
#pragma unroll
                for (int j = 0; j < 4; j++) {
                    size_t o = ((size_t)bb * 128 + ob + j) * 128;
                    P.y1[o + m] = f2bf_hi(ar[j]); P.y2[o + m] = f2bf_lo(ar[j]);
                    P.y1[o + 64 + m] = f2bf_hi(ai[j]); P.y2[o + 64 + m] = f2bf_lo(ai[j]);
                }
            }
            grid_barrier(P.gbar);

            // ======================= phase: idft+conv ======================
            {
                const u16* hc1 = P.ht1 + (size_t)cur * htplane;
                const u16* hc2 = P.ht2 + (size_t)cur * htplane;
                u16* hn1 = P.ht1 + (size_t)(cur ^ 1) * htplane;
                u16* hn2 = P.ht2 + (size_t)(cur ^ 1) * htplane;
                int wtr = (ly < 3) ? 1 : 0;
                u16* A1 = POOL;                  // [2][128*40] = 10240
                u16* A2 = POOL + 10240;
                u16* B1 = POOL + 20480;          // [2][64*40] = 5120
                u16* B2 = POOL + 25600;
                int rt = (bid & 7) * 64, b = bid >> 3;
                int wid = tid >> 6, l = tid & 63;
                int wo0 = (wid >> 1) * 32, wr0 = (wid & 1) * 32;
                int arow = (l & 15), kgrp = (l >> 4) * 8;
                int srow = tid >> 2, sseg = tid & 3;       // srow 0..63
                const u16* ya0 = P.y1 + ((size_t)b * 128 + srow) * 128 + sseg * 8;
                const u16* ya1 = ya0 + 64 * 128;
                const u16* yb0 = P.y2 + ((size_t)b * 128 + srow) * 128 + sseg * 8;
                const u16* yb1 = yb0 + 64 * 128;
                const u16* ca0 = P.cw1 + ((size_t)ly * 128 + srow) * 128 + sseg * 8;
                const u16* ca1 = ca0 + 64 * 128;
                const u16* cb0 = P.cw2 + ((size_t)ly * 128 + srow) * 128 + sseg * 8;
                const u16* cb1 = cb0 + 64 * 128;
                const u16* ga = P.gt1 + (size_t)(rt + srow) * 128 + sseg * 8;
                const u16* gb = P.gt2 + (size_t)(rt + srow) * 128 + sseg * 8;
                const u16* ha = hc1 + ((size_t)b * 512 + rt + srow) * 128 + sseg * 8;
                const u16* hb = hc2 + ((size_t)b * 512 + rt + srow) * 128 + sseg * 8;
                int soffA0 = srow * 40 + sseg * 8;
                int soffA1 = (srow + 64) * 40 + sseg * 8;
                f32x4 acc[2][2][2];
#pragma unroll
                for (int ot = 0; ot < 2; ot++)
#pragma unroll
                    for (int of = 0; of < 2; of++)
#pragma unroll
                        for (int rf = 0; rf < 2; rf++) acc[ot][of][rf] = (f32x4){0.f, 0.f, 0.f, 0.f};
                uint4 oA0, oA1r, oA2r, oA3, oB0, oB1;
                uint4 eA0, eA1r, eA2r, eA3, eB0, eB1;
#define ILOAD(chk, Q0, Q1, Q2, Q3, R0, R1)                                    \
    {   int k0_ = ((chk) & 3) * 32;                                           \
        if ((chk) < 4) {                                                      \
            Q0 = *(const uint4*)(ya0 + k0_); Q1 = *(const uint4*)(ya1 + k0_); \
            Q2 = *(const uint4*)(yb0 + k0_); Q3 = *(const uint4*)(yb1 + k0_); \
            R0 = *(const uint4*)(ga + k0_);  R1 = *(const uint4*)(gb + k0_);  \
        } else {                                                              \
            Q0 = *(const uint4*)(ca0 + k0_); Q1 = *(const uint4*)(ca1 + k0_); \
            Q2 = *(const uint4*)(cb0 + k0_); Q3 = *(const uint4*)(cb1 + k0_); \
            R0 = *(const uint4*)(ha + k0_);  R1 = *(const uint4*)(hb + k0_);  \
        } }
#define ISTORE(BUF, Q0, Q1, Q2, Q3, R0, R1)                                   \
    {   *(uint4*)(A1 + (BUF) * 5120 + soffA0) = Q0;                           \
        *(uint4*)(A1 + (BUF) * 5120 + soffA1) = Q1;                           \
        *(uint4*)(A2 + (BUF) * 5120 + soffA0) = Q2;                           \
        *(uint4*)(A2 + (BUF) * 5120 + soffA1) = Q3;                           \
        *(uint4*)(B1 + (BUF) * 2560 + soffA0) = R0;                           \
        *(uint4*)(B2 + (BUF) * 2560 + soffA0) = R1; }
#define ICOMP(BUF)                                                            \
    {   bf16x8 bfr[2][2];                                                     \
        _Pragma("unroll")                                                     \
        for (int rf = 0; rf < 2; rf++) {                                      \
            bfr[rf][0] = *(const bf16x8*)&B1[(BUF) * 2560 + (wr0 + rf * 16 + arow) * 40 + kgrp]; \
            bfr[rf][1] = *(const bf16x8*)&B2[(BUF) * 2560 + (wr0 + rf * 16 + arow) * 40 + kgrp]; \
        }                                                                     \
        _Pragma("unroll")                                                     \
        for (int ot = 0; ot < 2; ot++) {                                      \
        _Pragma("unroll")                                                     \
        for (int of = 0; of < 2; of++) {                                      \
            bf16x8 a1v = *(const bf16x8*)&A1[(BUF) * 5120 + (ot * 64 + wo0 + of * 16 + arow) * 40 + kgrp]; \
            bf16x8 a2v = *(const bf16x8*)&A2[(BUF) * 5120 + (ot * 64 + wo0 + of * 16 + arow) * 40 + kgrp]; \
            _Pragma("unroll")                                                 \
            for (int rf = 0; rf < 2; rf++) {                                  \
                acc[ot][of][rf] = MFMA16(a1v, bfr[rf][0], acc[ot][of][rf]);   \
                acc[ot][of][rf] = MFMA16(a1v, bfr[rf][1], acc[ot][of][rf]);   \
                acc[ot][of][rf] = MFMA16(a2v, bfr[rf][0], acc[ot][of][rf]);   \
            }                                                                 \
        } } }
                ILOAD(0, oA0, oA1r, oA2r, oA3, oB0, oB1)
                ISTORE(0, oA0, oA1r, oA2r, oA3, oB0, oB1)
                ILOAD(1, oA0, oA1r, oA2r, oA3, oB0, oB1)
                ILOAD(2, eA0, eA1r, eA2r, eA3, eB0, eB1)
                __syncthreads();
                for (int k = 0; k < 8; k += 2) {
                    ICOMP(0)
                    ISTORE(1, oA0, oA1r, oA2r, oA3, oB0, oB1)
                    if (k < 5) ILOAD(k + 3, oA0, oA1r, oA2r, oA3, oB0, oB1)
                    __syncthreads();
                    ICOMP(1)
                    if (k < 6) {
                        ISTORE(0, eA0, eA1r, eA2r, eA3, eB0, eB1)
                        if (k < 4) ILOAD(k + 4, eA0, eA1r, eA2r, eA3, eB0, eB1)
                    }
                    __syncthreads();
                }
#undef ILOAD
#undef ISTORE
#undef ICOMP
                __syncthreads();    // all LDS reads done; alias T over POOL
                u16* T1 = POOL;             // 128*66 = 8448
                u16* T2 = POOL + 8448;
#pragma unroll
                for (int ot = 0; ot < 2; ot++) {
#pragma unroll
                    for (int of = 0; of < 2; of++) {
                        int obl = ot * 64 + wo0 + of * 16 + (l >> 4) * 4;
#pragma unroll
                        for (int rf = 0; rf < 2; rf++) {
                            int rloc = wr0 + rf * 16 + (l & 15);
                            int r = rt + rloc;
                            float v0 = gelu_exact(acc[ot][of][rf][0] + P.conv_b[ly * 128 + obl + 0]);
                            float v1 = gelu_exact(acc[ot][of][rf][1] + P.conv_b[ly * 128 + obl + 1]);
                            float v2 = gelu_exact(acc[ot][of][rf][2] + P.conv_b[ly * 128 + obl + 2]);
                            float v3 = gelu_exact(acc[ot][of][rf][3] + P.conv_b[ly * 128 + obl + 3]);
                            ushort4 hv, lv;
                            hv.x = f2bf_hi(v0); hv.y = f2bf_hi(v1); hv.z = f2bf_hi(v2); hv.w = f2bf_hi(v3);
                            lv.x = f2bf_lo(v0); lv.y = f2bf_lo(v1); lv.z = f2bf_lo(v2); lv.w = f2bf_lo(v3);
                            size_t off = ((size_t)b * 512 + r) * 128 + obl;
                            *(ushort4*)&hn1[off] = hv;
                            *(ushort4*)&hn2[off] = lv;
                            if (wtr) {
                                T1[(obl + 0) * 66 + rloc] = hv.x; T1[(obl + 1) * 66 + rloc] = hv.y;
                                T1[(obl + 2) * 66 + rloc] = hv.z; T1[(obl + 3) * 66 + rloc] = hv.w;
                                T2[(obl + 0) * 66 + rloc] = lv.x; T2[(obl + 1) * 66 + rloc] = lv.y;
                                T2[(obl + 2) * 66 + rloc] = lv.z; T2[(obl + 3) * 66 + rloc] = lv.w;
                            }
                        }
                    }
                }
                if (wtr) {
                    __syncthreads();
#pragma unroll
                    for (int q = 0; q < 16; q++) {
                        int t = tid + q * 256;
                        int o = t >> 5, ru = t & 31;
                        u32 vh = *(const u32*)&T1[o * 66 + ru * 2];
                        u32 vl = *(const u32*)&T2[o * 66 + ru * 2];
                        size_t off = ((size_t)b * 128 + o) * 512 + rt + ru * 2;
                        *(u32*)&P.htc1[off] = vh;
                        *(u32*)&P.htc2[off] = vl;
                    }
                }
            }
            grid_barrier(P.gbar);
            cur ^= 1;
        }

        // ======================= phase: head (+fc0 next) ===================
        {
            int do_fc0 = (step < NSTEPS - 1) ? 1 : 0;
            u16* HA1 = POOL;                // 256*40
            u16* HA2 = POOL + 10240;
            u16* HB1 = POOL + 20480;        // 64*40
            u16* HB2 = POOL + 23040;
            float* fc2s = (float*)(POOL + 26624);   // 256 f
            float* fc1bs = (float*)(POOL + 27136);  // 256 f
            int b = bid >> 3, r0 = (bid & 7) * 64;
            int wid = tid >> 6, l = tid & 63;
            fc2s[tid] = P.fc2_w[tid];
            fc1bs[tid] = P.fc1_b[tid];
            int arow = l & 15, kgrp = (l >> 4) * 8;
            f32x4 acc[16];
#pragma unroll
            for (int jf = 0; jf < 16; jf++) acc[jf] = (f32x4){0.f, 0.f, 0.f, 0.f};
            for (int k0 = 0; k0 < 128; k0 += 32) {
                __syncthreads();
#pragma unroll
                for (int q = 0; q < 8; q++) {
                    int t = tid + q * 256;
                    int pl = t >> 10, j = (t >> 2) & 255, seg = t & 3;
                    const u16* src = (pl ? P.f12 : P.f11) + (size_t)j * 128 + k0 + seg * 8;
                    *(uint4*)((pl ? HA2 : HA1) + j * 40 + seg * 8) = *(const uint4*)src;
                }
#pragma unroll
                for (int q = 0; q < 2; q++) {
                    int t = tid + q * 256;
                    int pl = t >> 8, rr = (t >> 2) & 63, seg = t & 3;
                    const u16* src = (pl ? P.ht2 : P.ht1) + ((size_t)b * 512 + r0 + rr) * 128 + k0 + seg * 8;
                    *(uint4*)((pl ? HB2 : HB1) + rr * 40 + seg * 8) = *(const uint4*)src;
                }
                __syncthreads();
                int bo = (wid * 16 + arow) * 40 + kgrp;
                bf16x8 b1 = *(const bf16x8*)&HB1[bo];
                bf16x8 b2 = *(const bf16x8*)&HB2[bo];
#pragma unroll
                for (int jf = 0; jf < 16; jf++) {
                    int ao = (jf * 16 + arow) * 40 + kgrp;
                    bf16x8 a1 = *(const bf16x8*)&HA1[ao];
                    bf16x8 a2 = *(const bf16x8*)&HA2[ao];
                    acc[jf] = MFMA16(a1, b1, acc[jf]);
                    acc[jf] = MFMA16(a1, b2, acc[jf]);
                    acc[jf] = MFMA16(a2, b1, acc[jf]);
                }
            }
            __syncthreads();
            float dx = 0.0f;
#pragma unroll
            for (int jf = 0; jf < 16; jf++) {
                int jbase = jf * 16 + (l >> 4) * 4;
#pragma unroll
                for (int jj = 0; jj < 4; jj++) {
                    int j = jbase + jj;
                    dx += gelu_exact(acc[jf][jj] + fc1bs[j]) * fc2s[j];
                }
            }
            dx += __shfl_xor(dx, 16);
            dx += __shfl_xor(dx, 32);
            bool zlane = ((l >> 4) == 0);
            int rml = wid * 16 + arow;
            float zn = 0.0f;
            if (zlane) {
                int r = r0 + rml;
                zn = P.seq[((size_t)b * SEQROWS + step + 23) * NR + r] + dx + P.fc2_b[0];
                P.seq[((size_t)b * SEQROWS + step + 24) * NR + r] = zn;
                P.preds[((size_t)b * NSTEPS + step) * NR + r] = zn;
            }
            if (do_fc0) {
                float* win = (float*)POOL;                 // [24][64]
                float* wl  = (float*)POOL + 2048;          // [28][128]
                float* bl  = (float*)POOL + 2048 + 3584;   // [128]
                __syncthreads();   // dx-phase LDS reads done before aliasing
                for (int t = tid; t < 23 * 64; t += 256) {
                    int tr = t >> 6, c = t & 63;
                    win[tr * 64 + c] = P.seq[((size_t)b * SEQROWS + step + 1 + tr) * NR + r0 + c];
                }
                for (int t = tid; t < 28 * 128; t += 256) wl[t] = P.fc0_w[t];
                if (tid < 128) bl[tid] = P.fc0_b[tid];
                if (zlane) win[23 * 64 + rml] = zn;
                __syncthreads();
                int lane = tid & 63, wq = tid >> 6;
                int r = r0 + lane;
                float sv[24];
#pragma unroll
                for (int t = 0; t < 24; t++) sv[t] = win[t * 64 + lane];
                float tt = P.t_grid[b * 24 + 23] + (float)(step + 2);
                float ang24 = 6.28318530717958647692f * tt * (1.0f / 24.0f);
                float ang168 = 6.28318530717958647692f * tt * (1.0f / 168.0f);
                float s24 = sinf(ang24), c24 = cosf(ang24), s168 = sinf(ang168);
                float xc = (float)r * (1.0f / 511.0f);
                size_t rowoff = ((size_t)b * NR + r) * NW;
#pragma unroll 2
                for (int w0 = 0; w0 < 32; w0 += 2) {
                    float acc2[2];
#pragma unroll
                    for (int q = 0; q < 2; q++) {
                        int w = wq * 32 + w0 + q;
                        float a = bl[w];
#pragma unroll
                        for (int t = 0; t < 24; t++) a += sv[t] * wl[t * 128 + w];
                        a += s24 * wl[24 * 128 + w] + c24 * wl[25 * 128 + w]
                           + s168 * wl[26 * 128 + w] + xc * wl[27 * 128 + w];
                        acc2[q] = a;
                    }
                    u16 h0 = f2bf_hi(acc2[0]), h1 = f2bf_hi(acc2[1]);
                    u16 l0 = f2bf_lo(acc2[0]), l1 = f2bf_lo(acc2[1]);
                    size_t off = rowoff + wq * 32 + w0;
                    *(u32*)&P.ht1[off] = (u32)h0 | ((u32)h1 << 16);
                    *(u32*)&P.ht2[off] = (u32)l0 | ((u32)l1 << 16);
                    int w = wq * 32 + w0;
                    size_t coff = ((size_t)b * 128 + w) * 512 + r;
                    P.htc1[coff] = h0; P.htc1[coff + 512] = h1;
                    P.htc2[coff] = l0; P.htc2[coff + 512] = l1;
                }
            }
        }
        if (step < NSTEPS - 1) grid_barrier(P.gbar);
    }
}

// ---------------------------------------------------------------------------
extern "C" void kernel_launch(void* const* d_in, const int* in_sizes, int n_in,
                              void* d_out, int out_size, void* d_ws, size_t ws_size,
                              hipStream_t stream) {
    (void)in_sizes; (void)n_in; (void)out_size; (void)ws_size;
    const float* z       = (const float*)d_in[0];
    const float* t_grid  = (const float*)d_in[1];
    const float* fc0_w   = (const float*)d_in[2];
    const float* fc0_b   = (const float*)d_in[3];
    const float* spec_wr = (const float*)d_in[4];
    const float* spec_wi = (const float*)d_in[5];
    const float* conv_w  = (const float*)d_in[6];
    const float* conv_b  = (const float*)d_in[7];
    const float* fc1_w   = (const float*)d_in[8];
    const float* fc1_b   = (const float*)d_in[9];
    const float* fc2_w   = (const float*)d_in[10];
    const float* fc2_b   = (const float*)d_in[11];
    float* preds = (float*)d_out;

    char* p = (char*)d_ws;
    float* seq = (float*)p;  p += (size_t)NB * SEQROWS * NR * 4;
    u16* ht1 = (u16*)p;  p += (size_t)2 * NB * NR * NW * 2;   // [2 buf][b][r][c] hi
    u16* ht2 = (u16*)p;  p += (size_t)2 * NB * NR * NW * 2;   // lo
    u16* htc1 = (u16*)p; p += (size_t)NB * NW * NR * 2;       // [b][c][r] hi
    u16* htc2 = (u16*)p; p += (size_t)NB * NW * NR * 2;       // lo
    u16* x1  = (u16*)p;  p += (size_t)128 * 4096 * 2;
    u16* x2  = (u16*)p;  p += (size_t)128 * 4096 * 2;
    u16* y1  = (u16*)p;  p += (size_t)NB * NW * 128 * 2;
    u16* y2  = (u16*)p;  p += (size_t)NB * NW * 128 * 2;
    u16* f1  = (u16*)p;  p += (size_t)128 * 512 * 2;
    u16* f2  = (u16*)p;  p += (size_t)128 * 512 * 2;
    u16* gt1 = (u16*)p;  p += (size_t)512 * 128 * 2;
    u16* gt2 = (u16*)p;  p += (size_t)512 * 128 * 2;
    u16* wr1 = (u16*)p;  p += (size_t)NLAY * NM * NW * NW * 2;
    u16* wr2 = (u16*)p;  p += (size_t)NLAY * NM * NW * NW * 2;
    u16* wi1 = (u16*)p;  p += (size_t)NLAY * NM * NW * NW * 2;
    u16* wi2 = (u16*)p;  p += (size_t)NLAY * NM * NW * NW * 2;
    u16* cw1 = (u16*)p;  p += (size_t)NLAY * NW * NW * 2;
    u16* cw2 = (u16*)p;  p += (size_t)NLAY * NW * NW * 2;
    u16* f11 = (u16*)p;  p += (size_t)256 * 128 * 2;
    u16* f12 = (u16*)p;  p += (size_t)256 * 128 * 2;
    unsigned* gbar = (unsigned*)p; p += 64;                   // barrier state

    hipMemsetAsync(gbar, 0, 64, stream);
    build_tables_planes<<<256, 256, 0, stream>>>(f1, f2, gt1, gt2);
    prep_specw<<<512, 256, 0, stream>>>(spec_wr, spec_wi, wr1, wr2, wi1, wi2);
    prep_cw<<<256, 256, 0, stream>>>(conv_w, cw1, cw2);
    prep_fc1t<<<128, 256, 0, stream>>>(fc1_w, f11, f12);
    init_seq_kernel<<<(NB * NTH * NR) / 256, 256, 0, stream>>>(z, seq);

    PersistArgs P;
    P.f1 = f1; P.f2 = f2; P.gt1 = gt1; P.gt2 = gt2;
    P.wr1 = wr1; P.wr2 = wr2; P.wi1 = wi1; P.wi2 = wi2;
    P.cw1 = cw1; P.cw2 = cw2; P.conv_b = conv_b;
    P.f11 = f11; P.f12 = f12;
    P.fc1_b = fc1_b; P.fc2_w = fc2_w; P.fc2_b = fc2_b;
    P.t_grid = t_grid; P.fc0_w = fc0_w; P.fc0_b = fc0_b;
    P.seq = seq; P.preds = preds;
    P.ht1 = ht1; P.ht2 = ht2; P.htc1 = htc1; P.htc2 = htc2;
    P.x1 = x1; P.x2 = x2; P.y1 = y1; P.y2 = y2;
    P.gbar = gbar;
    fno_persist<<<dim3(256), dim3(256), 0, stream>>>(P);
}

// Round 13
// 3534.866 us; speedup vs baseline: 2.6374x; 2.6374x over previous
//
#include <hip/hip_runtime.h>
#include <math.h>

// LatentFNO: B=32, T=24, R=512, W=128, M=64 modes, 4 layers, 12 steps.
// Round 12: r11's grid barrier polled with ACQUIRE at agent scope -> a
// buffer_inv (full L2 invalidate) on EVERY poll from 255 blocks = 58us/
// barrier + cache-storm (9.1ms total). Fix: RELAXED polls (agent-scope
// loads bypass non-coherent L2 via sc bits, so still correct), RELEASE
// on arrive, ONE acquire fence on exit, counter/gen on separate lines.
// All phase bodies byte-identical to r12 (math: exact 3-term bf16 split).

#define NB 32
#define NR 512
#define NW 128
#define NM 64
#define NTH 24
#define NLAY 4
#define NSTEPS 12
#define SEQROWS 36

typedef unsigned short u16;
typedef unsigned int u32;
typedef __attribute__((ext_vector_type(8))) short bf16x8;
typedef __attribute__((ext_vector_type(4))) float f32x4;
#define MFMA16(a, b, c) __builtin_amdgcn_mfma_f32_16x16x32_bf16((a), (b), (c), 0, 0, 0)

__device__ __forceinline__ float gelu_exact(float x) {
    return 0.5f * x * (1.0f + erff(x * 0.70710678118654752f));
}
__device__ __forceinline__ float bf2f(u16 u) {
    union { u32 i; float f; } v; v.i = ((u32)u) << 16; return v.f;
}
__device__ __forceinline__ u16 f2bf_hi(float x) {
    union { float f; u32 i; } v; v.f = x; return (u16)(v.i >> 16);
}
__device__ __forceinline__ u16 f2bf_lo(float x) {
    float h = bf2f(f2bf_hi(x));
    return f2bf_hi(x - h);
}
__device__ __forceinline__ bf16x8 negbf(bf16x8 a) {
#pragma unroll
    for (int i = 0; i < 8; i++) a[i] ^= (short)0x8000;
    return a;
}

// Grid barrier: bar[0]=arrive counter, bar[32] (128B away)=generation.
// 256 blocks, 1/CU, co-resident by construction.
// Poll with RELAXED (agent-scope load bypasses non-coherent L2 -> fresh
// value, NO per-poll buffer_inv); one acquire fence after release observed.
__device__ __forceinline__ void grid_barrier(unsigned* bar) {
    __syncthreads();
    if (threadIdx.x == 0) {
        unsigned my = __hip_atomic_load(&bar[32], __ATOMIC_RELAXED, __HIP_MEMORY_SCOPE_AGENT);
        unsigned prev = __hip_atomic_fetch_add(&bar[0], 1u, __ATOMIC_RELEASE, __HIP_MEMORY_SCOPE_AGENT);
        if (prev == 255u) {
            __hip_atomic_store(&bar[0], 0u, __ATOMIC_RELAXED, __HIP_MEMORY_SCOPE_AGENT);
            __hip_atomic_store(&bar[32], my + 1u, __ATOMIC_RELEASE, __HIP_MEMORY_SCOPE_AGENT);
        } else {
            while (__hip_atomic_load(&bar[32], __ATOMIC_RELAXED, __HIP_MEMORY_SCOPE_AGENT) == my) {
                __builtin_amdgcn_s_sleep(2);
            }
        }
        __builtin_amdgcn_fence(__ATOMIC_ACQUIRE, "agent");   // one inv, not per-poll
    }
    __syncthreads();
}

// ---------------------------------------------------------------------------
// Setup kernels (unchanged)
// ---------------------------------------------------------------------------
__global__ void build_tables_planes(u16* __restrict__ f1, u16* __restrict__ f2,
                                    u16* __restrict__ gt1, u16* __restrict__ gt2) {
    int idx = blockIdx.x * 256 + threadIdx.x;   // 65536: mc*512 + r
    int mc = idx >> 9, r = idx & 511, m = mc & 63;
    int p = (m * r) & 511;
    float a = (float)p * (1.0f / 256.0f);
    float c = cospif(a), s = sinpif(a);
    float Fv = (mc < 64) ? c : -s;
    float cm = (m == 0) ? (1.0f / 512.0f) : (2.0f / 512.0f);
    float Gv = (mc < 64) ? cm * c : ((m == 0) ? 0.0f : -cm * s);
    f1[idx] = f2bf_hi(Fv); f2[idx] = f2bf_lo(Fv);
    size_t g = (size_t)r * 128 + mc;
    gt1[g] = f2bf_hi(Gv); gt2[g] = f2bf_lo(Gv);
}

__global__ __launch_bounds__(256) void prep_specw(const float* __restrict__ wr, const float* __restrict__ wi,
                           u16* __restrict__ wr1, u16* __restrict__ wr2,
                           u16* __restrict__ wi1, u16* __restrict__ wi2) {
    __shared__ float tile[128][65];
    int l = blockIdx.x >> 7, o = blockIdx.x & 127;
    int tid = threadIdx.x;
    size_t sbase = (size_t)l * 1048576 + (size_t)o * 64;
    size_t dbase = (size_t)l * 64 * 16384 + (size_t)o * 128;
    for (int pass = 0; pass < 2; pass++) {
        const float* src = pass ? wi : wr;
        u16* d1 = pass ? wi1 : wr1;
        u16* d2 = pass ? wi2 : wr2;
        if (pass) __syncthreads();
        for (int e = tid; e < 8192; e += 256) {
            int i = e >> 6, m = e & 63;
            tile[i][m] = src[sbase + (size_t)i * 8192 + m];
        }
        __syncthreads();
        for (int e = tid; e < 4096; e += 256) {
            int m = e >> 6, i2 = (e & 63) * 2;
            float v0 = tile[i2][m], v1 = tile[i2 + 1][m];
            u32 hh = (u32)f2bf_hi(v0) | ((u32)f2bf_hi(v1) << 16);
            u32 ll = (u32)f2bf_lo(v0) | ((u32)f2bf_lo(v1) << 16);
            size_t d = dbase + (size_t)m * 16384 + i2;
            *(u32*)&d1[d] = hh;
            *(u32*)&d2[d] = ll;
        }
    }
}

__global__ void prep_cw(const float* __restrict__ cw, u16* __restrict__ c1, u16* __restrict__ c2) {
    int idx = blockIdx.x * 256 + threadIdx.x;   // 65536
    float v = cw[idx];
    c1[idx] = f2bf_hi(v); c2[idx] = f2bf_lo(v);
}

__global__ void prep_fc1t(const float* __restrict__ fc1_w,
                          u16* __restrict__ f11, u16* __restrict__ f12) {
    int idx = blockIdx.x * 256 + threadIdx.x;   // 32768: j*128 + c
    int j = idx >> 7, c = idx & 127;
    float v = fc1_w[(size_t)c * 256 + j];
    f11[idx] = f2bf_hi(v); f12[idx] = f2bf_lo(v);
}

__global__ void init_seq_kernel(const float* __restrict__ z, float* __restrict__ seq) {
    int idx = blockIdx.x * 256 + threadIdx.x;    // < 32*24*512
    int b = idx / (NTH * NR);
    int rem = idx - b * (NTH * NR);
    seq[(size_t)b * SEQROWS * NR + rem] = z[idx];
}

// ---------------------------------------------------------------------------
// Persistent kernel: whole 12-step rollout, 156 grid barriers.
// 256 blocks x 256 threads (1/CU). POOL = 70144 B shared, re-carved per phase.
// ---------------------------------------------------------------------------
struct PersistArgs {
    const u16 *f1, *f2, *gt1, *gt2;
    const u16 *wr1, *wr2, *wi1, *wi2;
    const u16 *cw1, *cw2;
    const float *conv_b;
    const u16 *f11, *f12;
    const float *fc1_b, *fc2_w, *fc2_b, *t_grid, *fc0_w, *fc0_b;
    float *seq, *preds;
    u16 *ht1, *ht2, *htc1, *htc2, *x1, *x2, *y1, *y2;
    unsigned *gbar;
};

__global__ __launch_bounds__(256, 1) void fno_persist(PersistArgs P) {
    __shared__ __align__(16) u16 POOL[35072];   // 70144 B
    const int bid = blockIdx.x;
    const int tid = threadIdx.x;
    const size_t htplane = (size_t)NB * NR * NW;

    // ======================= phase: fc0 (step 0) ===========================
    {
        float* wlds = (float*)POOL;             // 28*128
        float* blds = (float*)POOL + 3584;      // 128
        int b = bid >> 3, rblk = bid & 7;
        for (int t = tid; t < 28 * 128; t += 256) wlds[t] = P.fc0_w[t];
        if (tid < 128) blds[tid] = P.fc0_b[tid];
        __syncthreads();
        int lane = tid & 63, wq = tid >> 6;
        int r = rblk * 64 + lane;
        float sv[24];
        const float* sp = P.seq + ((size_t)b * SEQROWS + 0) * NR + r;
#pragma unroll
        for (int t = 0; t < 24; t++) sv[t] = sp[(size_t)t * NR];
        float tt = P.t_grid[b * 24 + 23] + 1.0f;
        float ang24 = 6.28318530717958647692f * tt * (1.0f / 24.0f);
        float ang168 = 6.28318530717958647692f * tt * (1.0f / 168.0f);
        float s24 = sinf(ang24), c24 = cosf(ang24), s168 = sinf(ang168);
        float xc = (float)r * (1.0f / 511.0f);
        size_t rowoff = ((size_t)b * NR + r) * NW;
#pragma unroll 2
        for (int w0 = 0; w0 < 32; w0 += 2) {
            float acc2[2];
#pragma unroll
            for (int q = 0; q < 2; q++) {
                int w = wq * 32 + w0 + q;
                float acc = blds[w];
#pragma unroll
                for (int t = 0; t < 24; t++) acc += sv[t] * wlds[t * 128 + w];
                acc += s24 * wlds[24 * 128 + w] + c24 * wlds[25 * 128 + w]
                     + s168 * wlds[26 * 128 + w] + xc * wlds[27 * 128 + w];
                acc2[q] = acc;
            }
            u16 h0 = f2bf_hi(acc2[0]), h1 = f2bf_hi(acc2[1]);
            u16 l0 = f2bf_lo(acc2[0]), l1 = f2bf_lo(acc2[1]);
            size_t off = rowoff + wq * 32 + w0;
            *(u32*)&P.ht1[off] = (u32)h0 | ((u32)h1 << 16);
            *(u32*)&P.ht2[off] = (u32)l0 | ((u32)l1 << 16);
            int w = wq * 32 + w0;
            size_t coff = ((size_t)b * 128 + w) * 512 + r;
            P.htc1[coff] = h0; P.htc1[coff + 512] = h1;
            P.htc2[coff] = l0; P.htc2[coff + 512] = l1;
        }
    }
    grid_barrier(P.gbar);

    for (int step = 0; step < NSTEPS; step++) {
        int cur = 0;
        for (int ly = 0; ly < NLAY; ly++) {
            // ======================= phase: dft ============================
            {
                u16* A1 = POOL;                  // [2][1280]
                u16* A2 = POOL + 2560;
                u16* B1 = POOL + 5120;           // [2][2560]
                u16* B2 = POOL + 10240;
                int bx = bid & 63;
                int mct = (bid >> 6) * 32;
                int b = bx >> 1, ch = bx & 1;
                int wid = tid >> 6, l = tid & 63;
                int wm0 = (wid >> 1) * 16, wn0 = (wid & 1) * 32;
                int arow = (l & 15), kgrp = (l >> 4) * 8;
                f32x4 acc0 = {0.f, 0.f, 0.f, 0.f}, acc1 = {0.f, 0.f, 0.f, 0.f};
                int pa_pl = tid >> 7, pa_row = (tid >> 2) & 31, pa_seg = tid & 3;
                const u16* asrc = (pa_pl ? P.f2 : P.f1) + (size_t)(mct + pa_row) * 512 + pa_seg * 8;
                int aoff = pa_row * 40 + pa_seg * 8;
                int b_row = (tid >> 2) & 63, b_seg = tid & 3;
                const u16* bsrc1 = P.htc1 + ((size_t)b * 128 + ch * 64 + b_row) * 512 + b_seg * 8;
                const u16* bsrc2 = P.htc2 + ((size_t)b * 128 + ch * 64 + b_row) * 512 + b_seg * 8;
                int boff = b_row * 40 + b_seg * 8;
                u16* adst = (pa_pl ? A2 : A1) + aoff;
                uint4 raO, rbO0, rbO1, raE, rbE0, rbE1;
                raO = *(const uint4*)(asrc); rbO0 = *(const uint4*)(bsrc1); rbO1 = *(const uint4*)(bsrc2);
                *(uint4*)(adst) = raO;
                *(uint4*)(B1 + boff) = rbO0;
                *(uint4*)(B2 + boff) = rbO1;
                raO = *(const uint4*)(asrc + 32); rbO0 = *(const uint4*)(bsrc1 + 32); rbO1 = *(const uint4*)(bsrc2 + 32);
                raE = *(const uint4*)(asrc + 64); rbE0 = *(const uint4*)(bsrc1 + 64); rbE1 = *(const uint4*)(bsrc2 + 64);
                __syncthreads();
#define DFT_COMPUTE(BUF)                                                             \
    {   bf16x8 a1 = *(const bf16x8*)&A1[(BUF) * 1280 + (wm0 + arow) * 40 + kgrp];    \
        bf16x8 a2 = *(const bf16x8*)&A2[(BUF) * 1280 + (wm0 + arow) * 40 + kgrp];    \
        bf16x8 b10 = *(const bf16x8*)&B1[(BUF) * 2560 + (wn0 + arow) * 40 + kgrp];   \
        bf16x8 b20 = *(const bf16x8*)&B2[(BUF) * 2560 + (wn0 + arow) * 40 + kgrp];   \
        bf16x8 b11 = *(const bf16x8*)&B1[(BUF) * 2560 + (wn0 + 16 + arow) * 40 + kgrp]; \
        bf16x8 b21 = *(const bf16x8*)&B2[(BUF) * 2560 + (wn0 + 16 + arow) * 40 + kgrp]; \
        acc0 = MFMA16(a1, b10, acc0);                                                \
        acc0 = MFMA16(a1, b20, acc0);                                                \
        acc0 = MFMA16(a2, b10, acc0);                                                \
        acc1 = MFMA16(a1, b11, acc1);                                                \
        acc1 = MFMA16(a1, b21, acc1);                                                \
        acc1 = MFMA16(a2, b11, acc1); }
                for (int k = 0; k < 16; k += 2) {
                    DFT_COMPUTE(0)
                    *(uint4*)(adst + 1280) = raO;
                    *(uint4*)(B1 + 2560 + boff) = rbO0;
                    *(uint4*)(B2 + 2560 + boff) = rbO1;
                    if (k < 13) {
                        int ko = (k + 3) * 32;
                        raO = *(const uint4*)(asrc + ko); rbO0 = *(const uint4*)(bsrc1 + ko); rbO1 = *(const uint4*)(bsrc2 + ko);
                    }
                    __syncthreads();
                    DFT_COMPUTE(1)
                    if (k < 14) {
                        *(uint4*)(adst) = raE;
                        *(uint4*)(B1 + boff) = rbE0;
                        *(uint4*)(B2 + boff) = rbE1;
                        if (k < 12) {
                            int ko = (k + 4) * 32;
                            raE = *(const uint4*)(asrc + ko); rbE0 = *(const uint4*)(bsrc1 + ko); rbE1 = *(const uint4*)(bsrc2 + ko);
                        }
                    }
                    __syncthreads();
                }
#undef DFT_COMPUTE
                int mcr = mct + wm0 + (l >> 4) * 4;
                int n0 = bx * 64 + wn0 + (l & 15);
#pragma unroll
                for (int j = 0; j < 4; j++) {
                    size_t o0 = (size_t)(mcr + j) * 4096 + n0;
                    P.x1[o0] = f2bf_hi(acc0[j]); P.x2[o0] = f2bf_lo(acc0[j]);
                    size_t o1 = o0 + 16;
                    P.x1[o1] = f2bf_hi(acc1[j]); P.x2[o1] = f2bf_lo(acc1[j]);
                }
            }
            grid_barrier(P.gbar);

            // ======================= phase: modemix ========================
            {
                int m = bid & 63, oq = bid >> 6;
                int wid = tid >> 6, l = tid & 63;
                int wo0 = (wid >> 1) * 16, wb0 = (wid & 1) * 16;
                int arow = l & 15, kgrp = (l >> 4) * 8;
                size_t wbase = (((size_t)ly * 64 + m) * 128 + oq * 32) * 128;
#pragma unroll
                for (int q = 0; q < 16; q++) {
                    const int slab = q >> 1;
                    int rr = ((q & 1) << 4) + (tid >> 4);
                    int seg = tid & 15;
                    const u16* src;
                    if      (slab == 0) src = P.wr1 + wbase + (size_t)rr * 128 + seg * 8;
                    else if (slab == 1) src = P.wr2 + wbase + (size_t)rr * 128 + seg * 8;
                    else if (slab == 2) src = P.wi1 + wbase + (size_t)rr * 128 + seg * 8;
                    else if (slab == 3) src = P.wi2 + wbase + (size_t)rr * 128 + seg * 8;
                    else if (slab == 4) src = P.x1 + (size_t)m * 4096 + rr * 128 + seg * 8;
                    else if (slab == 5) src = P.x2 + (size_t)m * 4096 + rr * 128 + seg * 8;
                    else if (slab == 6) src = P.x1 + (size_t)(64 + m) * 4096 + rr * 128 + seg * 8;
                    else                src = P.x2 + (size_t)(64 + m) * 4096 + rr * 128 + seg * 8;
                    *(uint4*)&POOL[slab * 4352 + rr * 136 + seg * 8] = *(const uint4*)src;
                }
                __syncthreads();
                f32x4 ar = {0.f, 0.f, 0.f, 0.f}, ai = {0.f, 0.f, 0.f, 0.f};
                int aoB = (wo0 + arow) * 136 + kgrp;
                int boB = (wb0 + arow) * 136 + kgrp;
#pragma unroll
                for (int kg = 0; kg < 4; kg++) {
                    int ao = aoB + kg * 32;
                    int bo = boB + kg * 32;
                    bf16x8 Wr1 = *(const bf16x8*)&POOL[0 * 4352 + ao];
                    bf16x8 Wr2 = *(const bf16x8*)&POOL[1 * 4352 + ao];
                    bf16x8 Wi1 = *(const bf16x8*)&POOL[2 * 4352 + ao];
                    bf16x8 Wi2 = *(const bf16x8*)&POOL[3 * 4352 + ao];
                    bf16x8 Xr1 = *(const bf16x8*)&POOL[4 * 4352 + bo];
                    bf16x8 Xr2 = *(const bf16x8*)&POOL[5 * 4352 + bo];
                    bf16x8 Xi1 = *(const bf16x8*)&POOL[6 * 4352 + bo];
                    bf16x8 Xi2 = *(const bf16x8*)&POOL[7 * 4352 + bo];
                    bf16x8 nWi1 = negbf(Wi1), nWi2 = negbf(Wi2);
                    ar = MFMA16(Wr1, Xr1, ar); ar = MFMA16(Wr1, Xr2, ar); ar = MFMA16(Wr2, Xr1, ar);
                    ar = MFMA16(nWi1, Xi1, ar); ar = MFMA16(nWi1, Xi2, ar); ar = MFMA16(nWi2, Xi1, ar);
                    ai = MFMA16(Wi1, Xr1, ai); ai = MFMA16(Wi1, Xr2, ai); ai = MFMA16(Wi2, Xr1, ai);
                    ai = MFMA16(Wr1, Xi1, ai); ai = MFMA16(Wr1, Xi2, ai); ai = MFMA16(Wr2, Xi1, ai);
                }
                int ob = oq * 32 + wo0 + (l >> 4) * 4;
                int bb = wb0 + (l & 15);
#pragma unroll
                for (int j = 0; j < 4; j++) {
                    size_t o = ((size_t)bb * 128 + ob + j) * 128;
                    P.y1[o + m] = f2bf_hi(ar[j]); P.y2[o + m] = f2bf_lo(ar[j]);
                    P.y1[o + 64 + m] = f2bf_hi(ai[j]); P.y2[o + 64 + m] = f2bf_lo(ai[j]);
                }
            }
            grid_barrier(P.gbar);

            // ======================= phase: idft+conv ======================
            {
                const u16* hc1 = P.ht1 + (size_t)cur * htplane;
                const u16* hc2 = P.ht2 + (size_t)cur * htplane;
                u16* hn1 = P.ht1 + (size_t)(cur ^ 1) * htplane;
                u16* hn2 = P.ht2 + (size_t)(cur ^ 1) * htplane;
                int wtr = (ly < 3) ? 1 : 0;
                u16* A1 = POOL;                  // [2][128*40] = 10240
                u16* A2 = POOL + 10240;
                u16* B1 = POOL + 20480;          // [2][64*40] = 5120
                u16* B2 = POOL + 25600;
                int rt = (bid & 7) * 64, b = bid >> 3;
                int wid = tid >> 6, l = tid & 63;
                int wo0 = (wid >> 1) * 32, wr0 = (wid & 1) * 32;
                int arow = (l & 15), kgrp = (l >> 4) * 8;
                int srow = tid >> 2, sseg = tid & 3;       // srow 0..63
                const u16* ya0 = P.y1 + ((size_t)b * 128 + srow) * 128 + sseg * 8;
                const u16* ya1 = ya0 + 64 * 128;
                const u16* yb0 = P.y2 + ((size_t)b * 128 + srow) * 128 + sseg * 8;
                const u16* yb1 = yb0 + 64 * 128;
                const u16* ca0 = P.cw1 + ((size_t)ly * 128 + srow) * 128 + sseg * 8;
                const u16* ca1 = ca0 + 64 * 128;
                const u16* cb0 = P.cw2 + ((size_t)ly * 128 + srow) * 128 + sseg * 8;
                const u16* cb1 = cb0 + 64 * 128;
                const u16* ga = P.gt1 + (size_t)(rt + srow) * 128 + sseg * 8;
                const u16* gb = P.gt2 + (size_t)(rt + srow) * 128 + sseg * 8;
                const u16* ha = hc1 + ((size_t)b * 512 + rt + srow) * 128 + sseg * 8;
                const u16* hb = hc2 + ((size_t)b * 512 + rt + srow) * 128 + sseg * 8;
                int soffA0 = srow * 40 + sseg * 8;
                int soffA1 = (srow + 64) * 40 + sseg * 8;
                f32x4 acc[2][2][2];
#pragma unroll
                for (int ot = 0; ot < 2; ot++)
#pragma unroll
                    for (int of = 0; of < 2; of++)
#pragma unroll
                        for (int rf = 0; rf < 2; rf++) acc[ot][of][rf] = (f32x4){0.f, 0.f, 0.f, 0.f};
                uint4 oA0, oA1r, oA2r, oA3, oB0, oB1;
                uint4 eA0, eA1r, eA2r, eA3, eB0, eB1;
#define ILOAD(chk, Q0, Q1, Q2, Q3, R0, R1)                                    \
    {   int k0_ = ((chk) & 3) * 32;                                           \
        if ((chk) < 4) {                                                      \
            Q0 = *(const uint4*)(ya0 + k0_); Q1 = *(const uint4*)(ya1 + k0_); \
            Q2 = *(const uint4*)(yb0 + k0_); Q3 = *(const uint4*)(yb1 + k0_); \
            R0 = *(const uint4*)(ga + k0_);  R1 = *(const uint4*)(gb + k0_);  \
        } else {                                                              \
            Q0 = *(const uint4*)(ca0 + k0_); Q1 = *(const uint4*)(ca1 + k0_); \
            Q2 = *(const uint4*)(cb0 + k0_); Q3 = *(const uint4*)(cb1 + k0_); \
            R0 = *(const uint4*)(ha + k0_);  R1 = *(const uint4*)(hb + k0_);  \
        } }
#define ISTORE(BUF, Q0, Q1, Q2, Q3, R0, R1)                                   \
    {   *(uint4*)(A1 + (BUF) * 5120 + soffA0) = Q0;                           \
        *(uint4*)(A1 + (BUF) * 5120 + soffA1) = Q1;                           \
        *(uint4*)(A2 + (BUF) * 5120 + soffA0) = Q2;                           \
        *(uint4*)(A2 + (BUF) * 5120 + soffA1) = Q3;                           \
        *(uint4*)(B1 + (BUF) * 2560 + soffA0) = R0;                           \
        *(uint4*)(B2 + (BUF) * 2560 + soffA0) = R1; }
#define ICOMP(BUF)                                                            \
    {   bf16x8 bfr[2][2];                                                     \
        _Pragma("unroll")                                                     \
        for (int rf = 0; rf < 2; rf++) {                                      \
            bfr[rf][0] = *(const bf16x8*)&B1[(BUF) * 2560 + (wr0 + rf * 16 + arow) * 40 + kgrp]; \
            bfr[rf][1] = *(const bf16x8*)&B2[(BUF) * 2560 + (wr0 + rf * 16 + arow) * 40 + kgrp]; \
        }                                                                     \
        _Pragma("unroll")                                                     \
        for (int ot = 0; ot < 2; ot++) {                                      \
        _Pragma("unroll")                                                     \
        for (int of = 0; of < 2; of++) {                                      \
            bf16x8 a1v = *(const bf16x8*)&A1[(BUF) * 5120 + (ot * 64 + wo0 + of * 16 + arow) * 40 + kgrp]; \
            bf16x8 a2v = *(const bf16x8*)&A2[(BUF) * 5120 + (ot * 64 + wo0 + of * 16 + arow) * 40 + kgrp]; \
            _Pragma("unroll")                                                 \
            for (int rf = 0; rf < 2; rf++) {                                  \
                acc[ot][of][rf] = MFMA16(a1v, bfr[rf][0], acc[ot][of][rf]);   \
                acc[ot][of][rf] = MFMA16(a1v, bfr[rf][1], acc[ot][of][rf]);   \
                acc[ot][of][rf] = MFMA16(a2v, bfr[rf][0], acc[ot][of][rf]);   \
            }                                                                 \
        } } }
                ILOAD(0, oA0, oA1r, oA2r, oA3, oB0, oB1)
                ISTORE(0, oA0, oA1r, oA2r, oA3, oB0, oB1)
                ILOAD(1, oA0, oA1r, oA2r, oA3, oB0, oB1)
                ILOAD(2, eA0, eA1r, eA2r, eA3, eB0, eB1)
                __syncthreads();
                for (int k = 0; k < 8; k += 2) {
                    ICOMP(0)
                    ISTORE(1, oA0, oA1r, oA2r, oA3, oB0, oB1)
                    if (k < 5) ILOAD(k + 3, oA0, oA1r, oA2r, oA3, oB0, oB1)
                    __syncthreads();
                    ICOMP(1)
                    if (k < 6) {
                        ISTORE(0, eA0, eA1r, eA2r, eA3, eB0, eB1)
                        if (k < 4) ILOAD(k + 4, eA0, eA1r, eA2r, eA3, eB0, eB1)
                    }
                    __syncthreads();
                }
#undef ILOAD
#undef ISTORE
#undef ICOMP
                __syncthreads();    // all LDS reads done; alias T over POOL
                u16* T1 = POOL;             // 128*66 = 8448
                u16* T2 = POOL + 8448;
#pragma unroll
                for (int ot = 0; ot < 2; ot++) {
#pragma unroll
                    for (int of = 0; of < 2; of++) {
                        int obl = ot * 64 + wo0 + of * 16 + (l >> 4) * 4;
#pragma unroll
                        for (int rf = 0; rf < 2; rf++) {
                            int rloc = wr0 + rf * 16 + (l & 15);
                            int r = rt + rloc;
                            float v0 = gelu_exact(acc[ot][of][rf][0] + P.conv_b[ly * 128 + obl + 0]);
                            float v1 = gelu_exact(acc[ot][of][rf][1] + P.conv_b[ly * 128 + obl + 1]);
                            float v2 = gelu_exact(acc[ot][of][rf][2] + P.conv_b[ly * 128 + obl + 2]);
                            float v3 = gelu_exact(acc[ot][of][rf][3] + P.conv_b[ly * 128 + obl + 3]);
                            ushort4 hv, lv;
                            hv.x = f2bf_hi(v0); hv.y = f2bf_hi(v1); hv.z = f2bf_hi(v2); hv.w = f2bf_hi(v3);
                            lv.x = f2bf_lo(v0); lv.y = f2bf_lo(v1); lv.z = f2bf_lo(v2); lv.w = f2bf_lo(v3);
                            size_t off = ((size_t)b * 512 + r) * 128 + obl;
                            *(ushort4*)&hn1[off] = hv;
                            *(ushort4*)&hn2[off] = lv;
                            if (wtr) {
                                T1[(obl + 0) * 66 + rloc] = hv.x; T1[(obl + 1) * 66 + rloc] = hv.y;
                                T1[(obl + 2) * 66 + rloc] = hv.z; T1[(obl + 3) * 66 + rloc] = hv.w;
                                T2[(obl + 0) * 66 + rloc] = lv.x; T2[(obl + 1) * 66 + rloc] = lv.y;
                                T2[(obl + 2) * 66 + rloc] = lv.z; T2[(obl + 3) * 66 + rloc] = lv.w;
                            }
                        }
                    }
                }
                if (wtr) {
                    __syncthreads();
#pragma unroll
                    for (int q = 0; q < 16; q++) {
                        int t = tid + q * 256;
                        int o = t >> 5, ru = t & 31;
                        u32 vh = *(const u32*)&T1[o * 66 + ru * 2];
                        u32 vl = *(const u32*)&T2[o * 66 + ru * 2];
                        size_t off = ((size_t)b * 128 + o) * 512 + rt + ru * 2;
                        *(u32*)&P.htc1[off] = vh;
                        *(u32*)&P.htc2[off] = vl;
                    }
                }
            }
            grid_barrier(P.gbar);
            cur ^= 1;
        }

        // ======================= phase: head (+fc0 next) ===================
        {
            int do_fc0 = (step < NSTEPS - 1) ? 1 : 0;
            u16* HA1 = POOL;                // 256*40
            u16* HA2 = POOL + 10240;
            u16* HB1 = POOL + 20480;        // 64*40
            u16* HB2 = POOL + 23040;
            float* fc2s = (float*)(POOL + 26624);   // 256 f
            float* fc1bs = (float*)(POOL + 27136);  // 256 f
            int b = bid >> 3, r0 = (bid & 7) * 64;
            int wid = tid >> 6, l = tid & 63;
            fc2s[tid] = P.fc2_w[tid];
            fc1bs[tid] = P.fc1_b[tid];
            int arow = l & 15, kgrp = (l >> 4) * 8;
            f32x4 acc[16];
#pragma unroll
            for (int jf = 0; jf < 16; jf++) acc[jf] = (f32x4){0.f, 0.f, 0.f, 0.f};
            for (int k0 = 0; k0 < 128; k0 += 32) {
                __syncthreads();
#pragma unroll
                for (int q = 0; q < 8; q++) {
                    int t = tid + q * 256;
                    int pl = t >> 10, j = (t >> 2) & 255, seg = t & 3;
                    const u16* src = (pl ? P.f12 : P.f11) + (size_t)j * 128 + k0 + seg * 8;
                    *(uint4*)((pl ? HA2 : HA1) + j * 40 + seg * 8) = *(const uint4*)src;
                }
#pragma unroll
                for (int q = 0; q < 2; q++) {
                    int t = tid + q * 256;
                    int pl = t >> 8, rr = (t >> 2) & 63, seg = t & 3;
                    const u16* src = (pl ? P.ht2 : P.ht1) + ((size_t)b * 512 + r0 + rr) * 128 + k0 + seg * 8;
                    *(uint4*)((pl ? HB2 : HB1) + rr * 40 + seg * 8) = *(const uint4*)src;
                }
                __syncthreads();
                int bo = (wid * 16 + arow) * 40 + kgrp;
                bf16x8 b1 = *(const bf16x8*)&HB1[bo];
                bf16x8 b2 = *(const bf16x8*)&HB2[bo];
#pragma unroll
                for (int jf = 0; jf < 16; jf++) {
                    int ao = (jf * 16 + arow) * 40 + kgrp;
                    bf16x8 a1 = *(const bf16x8*)&HA1[ao];
                    bf16x8 a2 = *(const bf16x8*)&HA2[ao];
                    acc[jf] = MFMA16(a1, b1, acc[jf]);
                    acc[jf] = MFMA16(a1, b2, acc[jf]);
                    acc[jf] = MFMA16(a2, b1, acc[jf]);
                }
            }
            __syncthreads();
            float dx = 0.0f;
#pragma unroll
            for (int jf = 0; jf < 16; jf++) {
                int jbase = jf * 16 + (l >> 4) * 4;
#pragma unroll
                for (int jj = 0; jj < 4; jj++) {
                    int j = jbase + jj;
                    dx += gelu_exact(acc[jf][jj] + fc1bs[j]) * fc2s[j];
                }
            }
            dx += __shfl_xor(dx, 16);
            dx += __shfl_xor(dx, 32);
            bool zlane = ((l >> 4) == 0);
            int rml = wid * 16 + arow;
            float zn = 0.0f;
            if (zlane) {
                int r = r0 + rml;
                zn = P.seq[((size_t)b * SEQROWS + step + 23) * NR + r] + dx + P.fc2_b[0];
                P.seq[((size_t)b * SEQROWS + step + 24) * NR + r] = zn;
                P.preds[((size_t)b * NSTEPS + step) * NR + r] = zn;
            }
            if (do_fc0) {
                float* win = (float*)POOL;                 // [24][64]
                float* wl  = (float*)POOL + 2048;          // [28][128]
                float* bl  = (float*)POOL + 2048 + 3584;   // [128]
                __syncthreads();   // dx-phase LDS reads done before aliasing
                for (int t = tid; t < 23 * 64; t += 256) {
                    int tr = t >> 6, c = t & 63;
                    win[tr * 64 + c] = P.seq[((size_t)b * SEQROWS + step + 1 + tr) * NR + r0 + c];
                }
                for (int t = tid; t < 28 * 128; t += 256) wl[t] = P.fc0_w[t];
                if (tid < 128) bl[tid] = P.fc0_b[tid];
                if (zlane) win[23 * 64 + rml] = zn;
                __syncthreads();
                int lane = tid & 63, wq = tid >> 6;
                int r = r0 + lane;
                float sv[24];
#pragma unroll
                for (int t = 0; t < 24; t++) sv[t] = win[t * 64 + lane];
                float tt = P.t_grid[b * 24 + 23] + (float)(step + 2);
                float ang24 = 6.28318530717958647692f * tt * (1.0f / 24.0f);
                float ang168 = 6.28318530717958647692f * tt * (1.0f / 168.0f);
                float s24 = sinf(ang24), c24 = cosf(ang24), s168 = sinf(ang168);
                float xc = (float)r * (1.0f / 511.0f);
                size_t rowoff = ((size_t)b * NR + r) * NW;
#pragma unroll 2
                for (int w0 = 0; w0 < 32; w0 += 2) {
                    float acc2[2];
#pragma unroll
                    for (int q = 0; q < 2; q++) {
                        int w = wq * 32 + w0 + q;
                        float a = bl[w];
#pragma unroll
                        for (int t = 0; t < 24; t++) a += sv[t] * wl[t * 128 + w];
                        a += s24 * wl[24 * 128 + w] + c24 * wl[25 * 128 + w]
                           + s168 * wl[26 * 128 + w] + xc * wl[27 * 128 + w];
                        acc2[q] = a;
                    }
                    u16 h0 = f2bf_hi(acc2[0]), h1 = f2bf_hi(acc2[1]);
                    u16 l0 = f2bf_lo(acc2[0]), l1 = f2bf_lo(acc2[1]);
                    size_t off = rowoff + wq * 32 + w0;
                    *(u32*)&P.ht1[off] = (u32)h0 | ((u32)h1 << 16);
                    *(u32*)&P.ht2[off] = (u32)l0 | ((u32)l1 << 16);
                    int w = wq * 32 + w0;
                    size_t coff = ((size_t)b * 128 + w) * 512 + r;
                    P.htc1[coff] = h0; P.htc1[coff + 512] = h1;
                    P.htc2[coff] = l0; P.htc2[coff + 512] = l1;
                }
            }
        }
        if (step < NSTEPS - 1) grid_barrier(P.gbar);
    }
}

// ---------------------------------------------------------------------------
extern "C" void kernel_launch(void* const* d_in, const int* in_sizes, int n_in,
                              void* d_out, int out_size, void* d_ws, size_t ws_size,
                              hipStream_t stream) {
    (void)in_sizes; (void)n_in; (void)out_size; (void)ws_size;
    const float* z       = (const float*)d_in[0];
    const float* t_grid  = (const float*)d_in[1];
    const float* fc0_w   = (const float*)d_in[2];
    const float* fc0_b   = (const float*)d_in[3];
    const float* spec_wr = (const float*)d_in[4];
    const float* spec_wi = (const float*)d_in[5];
    const float* conv_w  = (const float*)d_in[6];
    const float* conv_b  = (const float*)d_in[7];
    const float* fc1_w   = (const float*)d_in[8];
    const float* fc1_b   = (const float*)d_in[9];
    const float* fc2_w   = (const float*)d_in[10];
    const float* fc2_b   = (const float*)d_in[11];
    float* preds = (float*)d_out;

    char* p = (char*)d_ws;
    float* seq = (float*)p;  p += (size_t)NB * SEQROWS * NR * 4;
    u16* ht1 = (u16*)p;  p += (size_t)2 * NB * NR * NW * 2;   // [2 buf][b][r][c] hi
    u16* ht2 = (u16*)p;  p += (size_t)2 * NB * NR * NW * 2;   // lo
    u16* htc1 = (u16*)p; p += (size_t)NB * NW * NR * 2;       // [b][c][r] hi
    u16* htc2 = (u16*)p; p += (size_t)NB * NW * NR * 2;       // lo
    u16* x1  = (u16*)p;  p += (size_t)128 * 4096 * 2;
    u16* x2  = (u16*)p;  p += (size_t)128 * 4096 * 2;
    u16* y1  = (u16*)p;  p += (size_t)NB * NW * 128 * 2;
    u16* y2  = (u16*)p;  p += (size_t)NB * NW * 128 * 2;
    u16* f1  = (u16*)p;  p += (size_t)128 * 512 * 2;
    u16* f2  = (u16*)p;  p += (size_t)128 * 512 * 2;
    u16* gt1 = (u16*)p;  p += (size_t)512 * 128 * 2;
    u16* gt2 = (u16*)p;  p += (size_t)512 * 128 * 2;
    u16* wr1 = (u16*)p;  p += (size_t)NLAY * NM * NW * NW * 2;
    u16* wr2 = (u16*)p;  p += (size_t)NLAY * NM * NW * NW * 2;
    u16* wi1 = (u16*)p;  p += (size_t)NLAY * NM * NW * NW * 2;
    u16* wi2 = (u16*)p;  p += (size_t)NLAY * NM * NW * NW * 2;
    u16* cw1 = (u16*)p;  p += (size_t)NLAY * NW * NW * 2;
    u16* cw2 = (u16*)p;  p += (size_t)NLAY * NW * NW * 2;
    u16* f11 = (u16*)p;  p += (size_t)256 * 128 * 2;
    u16* f12 = (u16*)p;  p += (size_t)256 * 128 * 2;
    unsigned* gbar = (unsigned*)p; p += 256;                  // barrier state (2 lines)

    hipMemsetAsync(gbar, 0, 256, stream);
    build_tables_planes<<<256, 256, 0, stream>>>(f1, f2, gt1, gt2);
    prep_specw<<<512, 256, 0, stream>>>(spec_wr, spec_wi, wr1, wr2, wi1, wi2);
    prep_cw<<<256, 256, 0, stream>>>(conv_w, cw1, cw2);
    prep_fc1t<<<128, 256, 0, stream>>>(fc1_w, f11, f12);
    init_seq_kernel<<<(NB * NTH * NR) / 256, 256, 0, stream>>>(z, seq);

    PersistArgs P;
    P.f1 = f1; P.f2 = f2; P.gt1 = gt1; P.gt2 = gt2;
    P.wr1 = wr1; P.wr2 = wr2; P.wi1 = wi1; P.wi2 = wi2;
    P.cw1 = cw1; P.cw2 = cw2; P.conv_b = conv_b;
    P.f11 = f11; P.f12 = f12;
    P.fc1_b = fc1_b; P.fc2_w = fc2_w; P.fc2_b = fc2_b;
    P.t_grid = t_grid; P.fc0_w = fc0_w; P.fc0_b = fc0_b;
    P.seq = seq; P.preds = preds;
    P.ht1 = ht1; P.ht2 = ht2; P.htc1 = htc1; P.htc2 = htc2;
    P.x1 = x1; P.x2 = x2; P.y1 = y1; P.y2 = y2;
    P.gbar = gbar;
    fno_persist<<<dim3(256), dim3(256), 0, stream>>>(P);
}